// Round 1
// baseline (8510.411 us; speedup 1.0000x reference)
//
#include <hip/hip_runtime.h>
#include <math.h>

// ---------------------------------------------------------------------------
// StyleGAN2 GSynthesisBlock (res 7: 64 -> 128), f32 reference-accurate impl.
// B=8, CIN=512, COUT=256, HIN=64, HOUT=128, D=512, NC=3
//
// conv0_up (transposed conv stride2 k3 + blur) is folded into ONE direct conv
// on the 128x128 grid: per output parity (py,px) there are exactly 3x3 input
// taps with composite weights  Wc[p][j] = sum_k flip(w0)[k] * K4[2j+1-p-k],
// K4 = [1,3,3,1]/4 per axis, input index iy = (oy>>1) + jy - 1 (clamped->0).
// ---------------------------------------------------------------------------

#define BATCH 8
#define CINC 512
#define COUTC 256

static constexpr size_t OFF_S0  = 0;                       // [8][512]
static constexpr size_t OFF_S1  = 4096;                    // [8][256]
static constexpr size_t OFF_S2  = 6144;                    // [8][256]
static constexpr size_t OFF_D0  = 8192;                    // [8][256]
static constexpr size_t OFF_D1  = 10240;                   // [8][256]
static constexpr size_t OFF_W0C = 12288;                   // [512][4][9][256]
static constexpr size_t OFF_W1T = OFF_W0C + (size_t)512*4*9*256;  // [256][9][256]
static constexpr size_t OFF_H   = OFF_W1T + (size_t)256*9*256;    // [8][256][128][128]
// total floats = 38,875,136  (155.5 MB)

static __device__ __forceinline__ float lrelu2(float v) {
    return (v > 0.f ? v : 0.2f * v) * 1.4142135623730951f;
}

// ---------------------------------------------------------------- styles ----
__global__ __launch_bounds__(256) void k_styles(
    const float* __restrict__ dl,
    const float* __restrict__ m0w, const float* __restrict__ m0b,
    const float* __restrict__ m1w, const float* __restrict__ m1b,
    const float* __restrict__ m2w, const float* __restrict__ m2b,
    float* __restrict__ ws)
{
    const float inv512 = 0.04419417382415922f;  // 1/sqrt(512)
    int t = blockIdx.x * 256 + threadIdx.x;     // 0..8191
    if (t < 4096) {                             // s0 [8][512]
        int b = t >> 9, i = t & 511;
        const float* d = dl + ((size_t)b * 14 + 9) * 512;
        const float* w = m0w + (size_t)i * 512;
        float a = 0.f;
        for (int k = 0; k < 512; ++k) a += d[k] * w[k];
        ws[OFF_S0 + t] = a * inv512 + m0b[i];
    } else if (t < 6144) {                      // s1 [8][256]
        int u = t - 4096; int b = u >> 8, o = u & 255;
        const float* d = dl + ((size_t)b * 14 + 10) * 512;
        const float* w = m1w + (size_t)o * 512;
        float a = 0.f;
        for (int k = 0; k < 512; ++k) a += d[k] * w[k];
        ws[OFF_S1 + u] = a * inv512 + m1b[o];
    } else if (t < 8192) {                      // s2 [8][256]
        int u = t - 6144; int b = u >> 8, o = u & 255;
        const float* d = dl + ((size_t)b * 14 + 11) * 512;
        const float* w = m2w + (size_t)o * 512;
        float a = 0.f;
        for (int k = 0; k < 512; ++k) a += d[k] * w[k];
        ws[OFF_S2 + u] = a * inv512 + m2b[o];
    }
}

// ----------------------------------------------------------------- demod ----
// d0[b,o] = rsqrt(sc0^2 * sum_i (sum_k w0[o,i,k]^2) * s0[b,i]^2 + 1e-8)
__global__ __launch_bounds__(256) void k_demod(
    const float* __restrict__ w0, const float* __restrict__ w1,
    float* __restrict__ ws)
{
    __shared__ float red[256];
    int t = threadIdx.x;
    int blk = blockIdx.x;
    if (blk < 256) {  // d0, CIN=512: thread handles i = t and t+256
        int o = blk;
        const float sc2 = 0.014731391274719744f * 0.014731391274719744f; // (1/sqrt(4608))^2
        float v0 = 0.f, v1 = 0.f;
        {
            const float* p = w0 + ((size_t)o * 512 + t) * 9;
            for (int k = 0; k < 9; ++k) v0 += p[k] * p[k];
        }
        {
            const float* p = w0 + ((size_t)o * 512 + t + 256) * 9;
            for (int k = 0; k < 9; ++k) v1 += p[k] * p[k];
        }
        for (int b = 0; b < 8; ++b) {
            float sa = ws[OFF_S0 + (size_t)b * 512 + t];
            float sb = ws[OFF_S0 + (size_t)b * 512 + t + 256];
            red[t] = v0 * sa * sa + v1 * sb * sb;
            __syncthreads();
            for (int s = 128; s > 0; s >>= 1) {
                if (t < s) red[t] += red[t + s];
                __syncthreads();
            }
            if (t == 0) ws[OFF_D0 + (size_t)b * 256 + o] = rsqrtf(red[0] * sc2 + 1e-8f);
            __syncthreads();
        }
    } else {          // d1, CIN=256
        int o = blk - 256;
        const float sc2 = 0.020833333333333332f * 0.020833333333333332f; // (1/48)^2
        float v0 = 0.f;
        {
            const float* p = w1 + ((size_t)o * 256 + t) * 9;
            for (int k = 0; k < 9; ++k) v0 += p[k] * p[k];
        }
        for (int b = 0; b < 8; ++b) {
            float sa = ws[OFF_S1 + (size_t)b * 256 + t];
            red[t] = v0 * sa * sa;
            __syncthreads();
            for (int s = 128; s > 0; s >>= 1) {
                if (t < s) red[t] += red[t + s];
                __syncthreads();
            }
            if (t == 0) ws[OFF_D1 + (size_t)b * 256 + o] = rsqrtf(red[0] * sc2 + 1e-8f);
            __syncthreads();
        }
    }
}

// -------------------------------------------------- composite conv0 wgts ----
// w0c[i][py*2+px][jy*3+jx][o] = sc0 * sum_{ky,kx} w0[o,i,2-ky,2-kx]
//                                 * K4[2jy+1-py-ky] * K4[2jx+1-px-kx]
__global__ __launch_bounds__(256) void k_prepw0(
    const float* __restrict__ w0, float* __restrict__ ws)
{
    int i = blockIdx.x;     // 0..511
    int o = threadIdx.x;    // 0..255
    const float sc0 = 0.014731391274719744f;   // 1/sqrt(512*9)
    const float K4[4] = {0.25f, 0.75f, 0.75f, 0.25f};
    float f[3][3];
    const float* p = w0 + ((size_t)o * 512 + i) * 9;
    for (int ky = 0; ky < 3; ++ky)
        for (int kx = 0; kx < 3; ++kx)
            f[ky][kx] = p[(2 - ky) * 3 + (2 - kx)];
    for (int py = 0; py < 2; ++py)
        for (int px = 0; px < 2; ++px)
            for (int jy = 0; jy < 3; ++jy)
                for (int jx = 0; jx < 3; ++jx) {
                    float a = 0.f;
                    for (int ky = 0; ky < 3; ++ky) {
                        int my = 2 * jy + 1 - py - ky;
                        if (my < 0 || my > 3) continue;
                        for (int kx = 0; kx < 3; ++kx) {
                            int mx = 2 * jx + 1 - px - kx;
                            if (mx < 0 || mx > 3) continue;
                            a += f[ky][kx] * K4[my] * K4[mx];
                        }
                    }
                    ws[OFF_W0C + (((size_t)i * 4 + py * 2 + px) * 9 + jy * 3 + jx) * 256 + o] = a * sc0;
                }
}

// ------------------------------------------------------ transposed w1 -------
__global__ __launch_bounds__(256) void k_prepw1(
    const float* __restrict__ w1, float* __restrict__ ws)
{
    int i = blockIdx.x;     // 0..255
    int o = threadIdx.x;    // 0..255
    const float sc1 = 0.020833333333333332f;   // 1/sqrt(256*9)
    const float* p = w1 + ((size_t)o * 256 + i) * 9;
    for (int k = 0; k < 9; ++k)
        ws[OFF_W1T + ((size_t)i * 9 + k) * 256 + o] = p[k] * sc1;
}

// ------------------------------------------------------------- conv0_up -----
// fused: modulate, transposed conv, demod, blur, noise, bias, lrelu*sqrt2
__global__ __launch_bounds__(256) void k_conv0(
    const float* __restrict__ x, const float* __restrict__ noise0,
    const float* __restrict__ bias0, const float* __restrict__ ns0p,
    float* __restrict__ ws)
{
    __shared__ float xs[10][10];
    __shared__ __align__(16) float wl[576];   // [4][9][16]
    int blk = blockIdx.x;
    int og = blk & 15;
    int tile = (blk >> 4) & 63;
    int b = blk >> 10;
    int t = threadIdx.x;
    int ty = t >> 4, tx = t & 15;
    int oy0 = (tile >> 3) * 16, ox0 = (tile & 7) * 16;
    int o0 = og * 16;
    int r0 = oy0 >> 1, c0 = ox0 >> 1;
    int oy = oy0 + ty, ox = ox0 + tx;
    int pp = (oy & 1) * 2 + (ox & 1);
    int myrow = (oy >> 1) - r0 + 1;
    int mycol = (ox >> 1) - c0 + 1;

    float acc[16];
#pragma unroll
    for (int k = 0; k < 16; ++k) acc[k] = 0.f;

    const float* s0 = ws + OFF_S0 + (size_t)b * 512;
    const float* w0c = ws + OFF_W0C;

    for (int i = 0; i < 512; ++i) {
        float sv = s0[i];
        if (t < 100) {
            int r = t / 10, c = t - r * 10;
            int iy = r0 - 1 + r, ix = c0 - 1 + c;
            float v = 0.f;
            if ((unsigned)iy < 64u && (unsigned)ix < 64u)
                v = x[(((size_t)b * 512 + i) * 64 + iy) * 64 + ix] * sv;
            xs[r][c] = v;
        }
        const float* wsrc = w0c + (size_t)i * 4 * 9 * 256;
#pragma unroll
        for (int k = 0; k < 3; ++k) {
            int idx = t + k * 256;
            if (idx < 576) {
                int ppq = idx / 144;
                int rem = idx - ppq * 144;
                int tap = rem >> 4, oo = rem & 15;
                wl[idx] = wsrc[((size_t)ppq * 9 + tap) * 256 + o0 + oo];
            }
        }
        __syncthreads();
        const float4* w4 = (const float4*)(wl + pp * 144);
#pragma unroll
        for (int jy = 0; jy < 3; ++jy) {
#pragma unroll
            for (int jx = 0; jx < 3; ++jx) {
                float xv = xs[myrow - 1 + jy][mycol - 1 + jx];
                const float4* wp = w4 + (jy * 3 + jx) * 4;
                float4 wa = wp[0], wb = wp[1], wc = wp[2], wd = wp[3];
                acc[0]  += xv * wa.x; acc[1]  += xv * wa.y;
                acc[2]  += xv * wa.z; acc[3]  += xv * wa.w;
                acc[4]  += xv * wb.x; acc[5]  += xv * wb.y;
                acc[6]  += xv * wb.z; acc[7]  += xv * wb.w;
                acc[8]  += xv * wc.x; acc[9]  += xv * wc.y;
                acc[10] += xv * wc.z; acc[11] += xv * wc.w;
                acc[12] += xv * wd.x; acc[13] += xv * wd.y;
                acc[14] += xv * wd.z; acc[15] += xv * wd.w;
            }
        }
        __syncthreads();
    }

    float nz = ns0p[0] * noise0[((size_t)b * 128 + oy) * 128 + ox];
#pragma unroll
    for (int oo = 0; oo < 16; ++oo) {
        int o = o0 + oo;
        float d0v = ws[OFF_D0 + (size_t)b * 256 + o];
        float v = acc[oo] * d0v + nz + bias0[o];
        ws[OFF_H + (((size_t)b * 256 + o) * 128 + oy) * 128 + ox] = lrelu2(v);
    }
}

// ---------------------------------------------------------------- conv1 -----
__global__ __launch_bounds__(256) void k_conv1(
    const float* __restrict__ noise1, const float* __restrict__ bias1,
    const float* __restrict__ ns1p, float* __restrict__ out,
    float* __restrict__ ws)
{
    __shared__ float xs[18][18];
    __shared__ __align__(16) float wl[144];   // [9][16]
    int blk = blockIdx.x;
    int og = blk & 15;
    int tile = (blk >> 4) & 63;
    int b = blk >> 10;
    int t = threadIdx.x;
    int ty = t >> 4, tx = t & 15;
    int oy0 = (tile >> 3) * 16, ox0 = (tile & 7) * 16;
    int o0 = og * 16;
    int oy = oy0 + ty, ox = ox0 + tx;

    float acc[16];
#pragma unroll
    for (int k = 0; k < 16; ++k) acc[k] = 0.f;

    const float* s1 = ws + OFF_S1 + (size_t)b * 256;
    const float* h = ws + OFF_H;
    const float* w1t = ws + OFF_W1T;

    for (int i = 0; i < 256; ++i) {
        float sv = s1[i];
#pragma unroll
        for (int k = 0; k < 2; ++k) {
            int idx = t + k * 256;
            if (idx < 324) {
                int r = idx / 18, c = idx - r * 18;
                int iy = oy0 - 1 + r, ix = ox0 - 1 + c;
                float v = 0.f;
                if ((unsigned)iy < 128u && (unsigned)ix < 128u)
                    v = h[(((size_t)b * 256 + i) * 128 + iy) * 128 + ix] * sv;
                xs[r][c] = v;
            }
        }
        if (t < 144) {
            int tap = t >> 4, oo = t & 15;
            wl[t] = w1t[((size_t)i * 9 + tap) * 256 + o0 + oo];
        }
        __syncthreads();
        const float4* w4 = (const float4*)wl;
#pragma unroll
        for (int ky = 0; ky < 3; ++ky) {
#pragma unroll
            for (int kx = 0; kx < 3; ++kx) {
                float xv = xs[ty + ky][tx + kx];
                const float4* wp = w4 + (ky * 3 + kx) * 4;
                float4 wa = wp[0], wb = wp[1], wc = wp[2], wd = wp[3];
                acc[0]  += xv * wa.x; acc[1]  += xv * wa.y;
                acc[2]  += xv * wa.z; acc[3]  += xv * wa.w;
                acc[4]  += xv * wb.x; acc[5]  += xv * wb.y;
                acc[6]  += xv * wb.z; acc[7]  += xv * wb.w;
                acc[8]  += xv * wc.x; acc[9]  += xv * wc.y;
                acc[10] += xv * wc.z; acc[11] += xv * wc.w;
                acc[12] += xv * wd.x; acc[13] += xv * wd.y;
                acc[14] += xv * wd.z; acc[15] += xv * wd.w;
            }
        }
        __syncthreads();
    }

    float nz = ns1p[0] * noise1[((size_t)b * 128 + oy) * 128 + ox];
#pragma unroll
    for (int oo = 0; oo < 16; ++oo) {
        int o = o0 + oo;
        float d1v = ws[OFF_D1 + (size_t)b * 256 + o];
        float v = acc[oo] * d1v + nz + bias1[o];
        out[(((size_t)b * 256 + o) * 128 + oy) * 128 + ox] = lrelu2(v);
    }
}

// --------------------------------------------------------------- to_rgb -----
// rgb = (h2 * s2) @ (w2*sc2) + bias2 + upfirdn2(y)
__global__ __launch_bounds__(256) void k_torgb(
    const float* __restrict__ yin, const float* __restrict__ w2,
    const float* __restrict__ bias2, float* __restrict__ out,
    const float* __restrict__ ws)
{
    int idx = blockIdx.x * 256 + threadIdx.x;  // 0..131071
    int xq = idx & 127, yq = (idx >> 7) & 127, b = idx >> 14;

    const float* s2 = ws + OFF_S2 + (size_t)b * 256;
    const float* hp = out + (size_t)b * 256 * 16384 + (size_t)yq * 128 + xq;

    float a0 = 0.f, a1 = 0.f, a2 = 0.f;
    for (int o = 0; o < 256; ++o) {
        float hv = hp[(size_t)o * 16384];
        float sv = hv * s2[o];
        a0 += sv * w2[o];
        a1 += sv * w2[256 + o];
        a2 += sv * w2[512 + o];
    }

    // skip path: upfirdn up=2 of y with k_up (2x2 taps per output, clamp->0)
    int py = yq & 1, px = xq & 1;
    float wy0 = py ? 0.75f : 0.25f, wy1 = py ? 0.25f : 0.75f;
    float wx0 = px ? 0.75f : 0.25f, wx1 = px ? 0.25f : 0.75f;
    int iy0 = (yq >> 1) + (py ? 0 : -1), iy1 = iy0 + 1;
    int ix0 = (xq >> 1) + (px ? 0 : -1), ix1 = ix0 + 1;
    bool vy0 = (unsigned)iy0 < 64u, vy1 = (unsigned)iy1 < 64u;
    bool vx0 = (unsigned)ix0 < 64u, vx1 = (unsigned)ix1 < 64u;

    float* out1 = out + (size_t)33554432;
    for (int c = 0; c < 3; ++c) {
        const float* yb = yin + ((size_t)b * 3 + c) * 4096;
        float sk = 0.f;
        if (vy0 && vx0) sk += wy0 * wx0 * yb[iy0 * 64 + ix0];
        if (vy0 && vx1) sk += wy0 * wx1 * yb[iy0 * 64 + ix1];
        if (vy1 && vx0) sk += wy1 * wx0 * yb[iy1 * 64 + ix0];
        if (vy1 && vx1) sk += wy1 * wx1 * yb[iy1 * 64 + ix1];
        float a = (c == 0) ? a0 : (c == 1) ? a1 : a2;
        out1[(((size_t)b * 3 + c) * 128 + yq) * 128 + xq] = a * 0.0625f + bias2[c] + sk;
    }
}

// ---------------------------------------------------------------------------
extern "C" void kernel_launch(void* const* d_in, const int* in_sizes, int n_in,
                              void* d_out, int out_size, void* d_ws, size_t ws_size,
                              hipStream_t stream)
{
    const float* x       = (const float*)d_in[0];
    const float* dl      = (const float*)d_in[1];
    const float* yin     = (const float*)d_in[2];
    const float* noise0  = (const float*)d_in[3];
    const float* noise1  = (const float*)d_in[4];
    const float* w0      = (const float*)d_in[5];
    const float* m0w     = (const float*)d_in[6];
    const float* m0b     = (const float*)d_in[7];
    const float* bias0   = (const float*)d_in[8];
    const float* ns0     = (const float*)d_in[9];
    const float* w1      = (const float*)d_in[10];
    const float* m1w     = (const float*)d_in[11];
    const float* m1b     = (const float*)d_in[12];
    const float* bias1   = (const float*)d_in[13];
    const float* ns1     = (const float*)d_in[14];
    const float* w2      = (const float*)d_in[15];
    const float* m2w     = (const float*)d_in[16];
    const float* m2b     = (const float*)d_in[17];
    const float* bias2   = (const float*)d_in[18];

    float* ws  = (float*)d_ws;
    float* out = (float*)d_out;

    k_styles<<<32, 256, 0, stream>>>(dl, m0w, m0b, m1w, m1b, m2w, m2b, ws);
    k_demod <<<512, 256, 0, stream>>>(w0, w1, ws);
    k_prepw0<<<512, 256, 0, stream>>>(w0, ws);
    k_prepw1<<<256, 256, 0, stream>>>(w1, ws);
    k_conv0 <<<8192, 256, 0, stream>>>(x, noise0, bias0, ns0, ws);
    k_conv1 <<<8192, 256, 0, stream>>>(noise1, bias1, ns1, out, ws);
    k_torgb <<<512, 256, 0, stream>>>(yin, w2, bias2, out, ws);
}

// Round 4
// 1021.141 us; speedup vs baseline: 8.3342x; 8.3342x over previous
//
#include <hip/hip_runtime.h>
#include <math.h>

typedef short bf16x8 __attribute__((ext_vector_type(8)));
typedef float f32x4 __attribute__((ext_vector_type(4)));
typedef unsigned int u32;
typedef unsigned short u16;

// ---------------- workspace layout (bytes) ----------------
#define OFF_S0   0                              // [8][512] f32
#define OFF_S1   16384                          // [8][256] f32
#define OFF_S2   24576                          // [8][256] f32
#define OFF_D0   32768                          // [8][256] f32
#define OFF_D1   40960                          // [8][256] f32
#define OFF_W0C  65536                          // bf16 [4][9][16][256][40]
#define W0C_BYTES (4*9*16*256*40*2)
#define OFF_W1C  (OFF_W0C + W0C_BYTES)          // bf16 [9][8][256][40]
#define W1C_BYTES (9*8*256*40*2)
#define OFF_XMOD (OFF_W1C + W1C_BYTES)          // bf16 [8][64][64][512]
#define XMOD_BYTES (8*64*64*512*2)
#define OFF_HMOD (OFF_XMOD + XMOD_BYTES)        // bf16 [8][128][128][256]

static __device__ __forceinline__ float lrelu2(float v) {
    return (v > 0.f ? v : 0.2f * v) * 1.4142135623730951f;
}
static __device__ __forceinline__ u16 f2bf(float f) {
    u32 u = __float_as_uint(f);
    u += 0x7fffu + ((u >> 16) & 1u);
    return (u16)(u >> 16);
}
static __device__ __forceinline__ void gl_lds16(const void* g, void* l) {
    __builtin_amdgcn_global_load_lds((const __attribute__((address_space(1))) u32*)g,
                                     (__attribute__((address_space(3))) u32*)l, 16, 0, 0);
}

// ---------------- styles (f32) ----------------
__global__ __launch_bounds__(256) void k_styles(
    const float* __restrict__ dl,
    const float* __restrict__ m0w, const float* __restrict__ m0b,
    const float* __restrict__ m1w, const float* __restrict__ m1b,
    const float* __restrict__ m2w, const float* __restrict__ m2b,
    float* __restrict__ ws)
{
    const float inv512 = 0.04419417382415922f;
    int t = blockIdx.x * 256 + threadIdx.x;
    if (t < 4096) {
        int b = t >> 9, i = t & 511;
        const float* d = dl + ((size_t)b * 14 + 9) * 512;
        const float* w = m0w + (size_t)i * 512;
        float a = 0.f;
        for (int k = 0; k < 512; ++k) a += d[k] * w[k];
        ws[t] = a * inv512 + m0b[i];
    } else if (t < 6144) {
        int u = t - 4096; int b = u >> 8, o = u & 255;
        const float* d = dl + ((size_t)b * 14 + 10) * 512;
        const float* w = m1w + (size_t)o * 512;
        float a = 0.f;
        for (int k = 0; k < 512; ++k) a += d[k] * w[k];
        ws[4096 + u] = a * inv512 + m1b[o];
    } else if (t < 8192) {
        int u = t - 6144; int b = u >> 8, o = u & 255;
        const float* d = dl + ((size_t)b * 14 + 11) * 512;
        const float* w = m2w + (size_t)o * 512;
        float a = 0.f;
        for (int k = 0; k < 512; ++k) a += d[k] * w[k];
        ws[6144 + u] = a * inv512 + m2b[o];
    }
}

// ---------------- demod (f32) ----------------
__global__ __launch_bounds__(256) void k_demod(
    const float* __restrict__ w0, const float* __restrict__ w1,
    float* __restrict__ ws)
{
    __shared__ float red[256];
    int t = threadIdx.x;
    int blk = blockIdx.x;
    if (blk < 256) {
        int o = blk;
        const float sc2 = 0.014731391274719744f * 0.014731391274719744f;
        float v0 = 0.f, v1 = 0.f;
        { const float* p = w0 + ((size_t)o * 512 + t) * 9;
          for (int k = 0; k < 9; ++k) v0 += p[k] * p[k]; }
        { const float* p = w0 + ((size_t)o * 512 + t + 256) * 9;
          for (int k = 0; k < 9; ++k) v1 += p[k] * p[k]; }
        for (int b = 0; b < 8; ++b) {
            float sa = ws[(size_t)b * 512 + t];
            float sb = ws[(size_t)b * 512 + t + 256];
            red[t] = v0 * sa * sa + v1 * sb * sb;
            __syncthreads();
            for (int s = 128; s > 0; s >>= 1) {
                if (t < s) red[t] += red[t + s];
                __syncthreads();
            }
            if (t == 0) ws[8192 + (size_t)b * 256 + o] = rsqrtf(red[0] * sc2 + 1e-8f);
            __syncthreads();
        }
    } else {
        int o = blk - 256;
        const float sc2 = 0.020833333333333332f * 0.020833333333333332f;
        float v0 = 0.f;
        { const float* p = w1 + ((size_t)o * 256 + t) * 9;
          for (int k = 0; k < 9; ++k) v0 += p[k] * p[k]; }
        for (int b = 0; b < 8; ++b) {
            float sa = ws[4096 + (size_t)b * 256 + t];   // S1 (float idx 4096)
            red[t] = v0 * sa * sa;
            __syncthreads();
            for (int s = 128; s > 0; s >>= 1) {
                if (t < s) red[t] += red[t + s];
                __syncthreads();
            }
            if (t == 0) ws[10240 + (size_t)b * 256 + o] = rsqrtf(red[0] * sc2 + 1e-8f);
            __syncthreads();
        }
    }
}

// ---------------- composite conv0 weights -> bf16 padded ----------------
__global__ __launch_bounds__(256) void k_prepw0(
    const float* __restrict__ w0, char* __restrict__ wsb)
{
    int i = blockIdx.x;     // 0..511
    int o = threadIdx.x;    // 0..255
    const float sc0 = 0.014731391274719744f;
    const float K4[4] = {0.25f, 0.75f, 0.75f, 0.25f};
    float f[3][3];
    const float* p = w0 + ((size_t)o * 512 + i) * 9;
    for (int ky = 0; ky < 3; ++ky)
        for (int kx = 0; kx < 3; ++kx)
            f[ky][kx] = p[(2 - ky) * 3 + (2 - kx)];
    u16* W = (u16*)(wsb + OFF_W0C);
    int icb = i >> 5, icw = i & 31;
    for (int py = 0; py < 2; ++py)
        for (int px = 0; px < 2; ++px) {
            int par = py * 2 + px;
            for (int jy = 0; jy < 3; ++jy)
                for (int jx = 0; jx < 3; ++jx) {
                    float a = 0.f;
                    for (int ky = 0; ky < 3; ++ky) {
                        int my = 2 * jy + 1 - py - ky;
                        if (my < 0 || my > 3) continue;
                        for (int kx = 0; kx < 3; ++kx) {
                            int mx = 2 * jx + 1 - px - kx;
                            if (mx < 0 || mx > 3) continue;
                            a += f[ky][kx] * K4[my] * K4[mx];
                        }
                    }
                    int tap = jy * 3 + jx;
                    W[(((size_t)(par * 9 + tap) * 16 + icb) * 256 + o) * 40 + icw] = f2bf(a * sc0);
                }
        }
}

// ---------------- w1 -> bf16 padded ----------------
__global__ __launch_bounds__(256) void k_prepw1(
    const float* __restrict__ w1, char* __restrict__ wsb)
{
    int i = blockIdx.x;     // 0..255
    int o = threadIdx.x;    // 0..255
    const float sc1 = 0.020833333333333332f;
    u16* W = (u16*)(wsb + OFF_W1C);
    int icb = i >> 5, icw = i & 31;
    const float* p = w1 + ((size_t)o * 256 + i) * 9;
    for (int tap = 0; tap < 9; ++tap)
        W[(((size_t)tap * 8 + icb) * 256 + o) * 40 + icw] = f2bf(p[tap] * sc1);
}

// ---------------- x transpose+modulate -> bf16 [b][r][c][512] ----------------
__global__ __launch_bounds__(256) void k_xmod(
    const float* __restrict__ x, char* __restrict__ wsb)
{
    __shared__ u16 tile[64][72];
    int b = blockIdx.x >> 6, r = blockIdx.x & 63;
    int t = threadIdx.x;
    const float* s0 = (const float*)wsb + (size_t)b * 512;
    u16* xm = (u16*)(wsb + OFF_XMOD) + ((size_t)(b * 64 + r) * 64) * 512;
    for (int icc = 0; icc < 8; ++icc) {
        int ii = t >> 2, cq = t & 3;
        int ic = icc * 64 + ii;
        float sv = s0[ic];
        const float* xrow = x + ((size_t)(b * 512 + ic) * 64 + r) * 64;
        for (int u = 0; u < 4; ++u) {
            float4 v = *(const float4*)(xrow + cq * 16 + u * 4);
            int c = cq * 16 + u * 4;
            tile[c + 0][ii] = f2bf(v.x * sv);
            tile[c + 1][ii] = f2bf(v.y * sv);
            tile[c + 2][ii] = f2bf(v.z * sv);
            tile[c + 3][ii] = f2bf(v.w * sv);
        }
        __syncthreads();
        int c = t >> 2, part = t & 3;
        uint4* dst = (uint4*)(xm + (size_t)c * 512 + icc * 64 + part * 16);
        const uint4* sp = (const uint4*)(&tile[c][part * 16]);
        dst[0] = sp[0]; dst[1] = sp[1];
        __syncthreads();
    }
}

// ---------------- conv0: MFMA implicit GEMM per parity ----------------
// block: 128 pos (16x8 parity tile) x 128 oc; 4 waves of 64x64
__global__ __launch_bounds__(256) void k_conv0m(
    char* __restrict__ wsb, const float* __restrict__ noise0,
    const float* __restrict__ bias0, const float* __restrict__ ns0p)
{
    __shared__ char xb[2][14400];   // [18][10][40] bf16
    __shared__ char wb[2][10240];   // [128][40] bf16

    int bid = blockIdx.x;
    int rid = (bid & 7) * 256 + (bid >> 3);      // XCD-chunked
    int slice = rid >> 8;                        // 0..7 -> (par, octile)
    int par = slice >> 1, octile = slice & 1;
    int within = rid & 255;
    int b = within >> 5, tile = within & 31;
    int pr0 = (tile >> 3) * 16, pc0 = (tile & 7) * 8;
    int py = par >> 1, px = par & 1;

    int t = threadIdx.x;
    int l = t & 63, w = t >> 6;
    int wp = w >> 1, wo = w & 1;
    int l15 = l & 15, icq = l >> 4;

    const u16* XM = (const u16*)(wsb + OFF_XMOD) + (size_t)b * 64 * 64 * 512;
    const char* WB = wsb + OFF_W0C;
    const float* wsf = (const float*)wsb;

    // X-halo chunk precompute (3 chunks/thread)
    int xdst[3]; const u16* xsrc[3]; bool xok[3]; bool xin[3];
    for (int j = 0; j < 3; ++j) {
        int q = t + j * 256;
        xok[j] = q < 720;
        int cell = q >> 2, part = q & 3;
        int hr = cell / 10, hc = cell - hr * 10;
        int ir = pr0 + hr - 1, icol = pc0 + hc - 1;
        xin[j] = (ir >= 0 && ir < 64 && icol >= 0 && icol < 64);
        xsrc[j] = XM + (ptrdiff_t)(ir * 64 + icol) * 512 + part * 8;
        xdst[j] = cell * 80 + part * 16;
    }

    int arow = wp * 8 + (l15 >> 3);
    int acol = l15 & 7;
    int aoff0 = (arow * 10 + acol) * 80 + icq * 16;
    int boff0 = (wo * 64 + l15) * 80 + icq * 16;

    f32x4 acc[4][4];
#pragma unroll
    for (int pf = 0; pf < 4; ++pf)
#pragma unroll
        for (int of = 0; of < 4; ++of) acc[pf][of] = (f32x4){0.f, 0.f, 0.f, 0.f};

    uint4 xr[3];

    // prologue: stage X(0) and W(0,0)
#pragma unroll
    for (int j = 0; j < 3; ++j) {
        uint4 z = {0, 0, 0, 0};
        xr[j] = (xok[j] && xin[j]) ? *(const uint4*)(xsrc[j]) : z;
    }
#pragma unroll
    for (int j = 0; j < 3; ++j)
        if (xok[j]) *(uint4*)(xb[0] + xdst[j]) = xr[j];
    {
        const char* wsrc = WB + (size_t)((par * 9 + 0) * 16 + 0) * 20480 + octile * 10240;
        for (int off = w * 1024; off < 10240; off += 4096)
            gl_lds16(wsrc + off + l * 16, wb[0] + off);
    }
    __syncthreads();

    for (int icb = 0; icb < 16; ++icb) {
        // prefetch X(icb+1) into regs
        if (icb + 1 < 16) {
#pragma unroll
            for (int j = 0; j < 3; ++j) {
                uint4 z = {0, 0, 0, 0};
                xr[j] = (xok[j] && xin[j]) ? *(const uint4*)(xsrc[j] + (icb + 1) * 32) : z;
            }
        }
#pragma unroll
        for (int tap = 0; tap < 9; ++tap) {
            int step = icb * 9 + tap;
            // prefetch next W chunk
            int ntap = tap + 1, nicb = icb;
            if (ntap == 9) { ntap = 0; nicb = icb + 1; }
            if (nicb < 16) {
                const char* wsrc = WB + (size_t)((par * 9 + ntap) * 16 + nicb) * 20480 + octile * 10240;
                char* wdst = wb[(step + 1) & 1];
                for (int off = w * 1024; off < 10240; off += 4096)
                    gl_lds16(wsrc + off + l * 16, wdst + off);
            }
            // write X(icb+1) to other buffer at end of this icb
            if (tap == 8 && icb + 1 < 16) {
#pragma unroll
                for (int j = 0; j < 3; ++j)
                    if (xok[j]) *(uint4*)(xb[(icb + 1) & 1] + xdst[j]) = xr[j];
            }
            // compute
            {
                const char* xc = xb[icb & 1];
                const char* wc = wb[step & 1];
                int jy = tap / 3, jx = tap - jy * 3;
                int ab = aoff0 + jy * 800 + jx * 80;
                bf16x8 af[4], bfr[4];
#pragma unroll
                for (int pf = 0; pf < 4; ++pf)
                    af[pf] = *(const bf16x8*)(xc + ab + pf * 1600);
#pragma unroll
                for (int of = 0; of < 4; ++of)
                    bfr[of] = *(const bf16x8*)(wc + boff0 + of * 1280);
#pragma unroll
                for (int pf = 0; pf < 4; ++pf)
#pragma unroll
                    for (int of = 0; of < 4; ++of)
                        acc[pf][of] = __builtin_amdgcn_mfma_f32_16x16x32_bf16(
                            af[pf], bfr[of], acc[pf][of], 0, 0, 0);
            }
            __syncthreads();
        }
    }

    // epilogue: demod + noise + bias + lrelu, then *s1 -> hmod bf16
    float ns0 = ns0p[0];
    float d0v[4], s1v[4], bv[4];
    int ocg[4];
#pragma unroll
    for (int of = 0; of < 4; ++of) {
        int oc = octile * 128 + wo * 64 + of * 16 + l15;
        ocg[of] = oc;
        d0v[of] = wsf[8192 + b * 256 + oc];
        s1v[of] = wsf[4096 + b * 256 + oc];
        bv[of]  = bias0[oc];
    }
    u16* HM = (u16*)(wsb + OFF_HMOD) + (size_t)b * 128 * 128 * 256;
#pragma unroll
    for (int pf = 0; pf < 4; ++pf) {
#pragma unroll
        for (int r = 0; r < 4; ++r) {
            int pos = wp * 64 + pf * 16 + icq * 4 + r;
            int pr = pr0 + (pos >> 3), pc = pc0 + (pos & 7);
            int oy = pr * 2 + py, ox = pc * 2 + px;
            float nz = ns0 * noise0[((size_t)b * 128 + oy) * 128 + ox];
            u16* hrow = HM + ((size_t)oy * 128 + ox) * 256;
#pragma unroll
            for (int of = 0; of < 4; ++of) {
                float v = lrelu2(acc[pf][of][r] * d0v[of] + nz + bv[of]);
                hrow[ocg[of]] = f2bf(v * s1v[of]);
            }
        }
    }
}

// ---------------- conv1: MFMA implicit GEMM ----------------
__global__ __launch_bounds__(256) void k_conv1m(
    char* __restrict__ wsb, const float* __restrict__ noise1,
    const float* __restrict__ bias1, const float* __restrict__ ns1p,
    float* __restrict__ out)
{
    __shared__ char xb[2][14400];
    __shared__ char wb[2][10240];

    int bid = blockIdx.x;
    int rid = (bid & 7) * 256 + (bid >> 3);
    int octile = rid >> 10;
    int within = rid & 1023;
    int b = within >> 7, tile = within & 127;
    int or0 = (tile >> 4) * 16, col0 = (tile & 15) * 8;

    int t = threadIdx.x;
    int l = t & 63, w = t >> 6;
    int wp = w >> 1, wo = w & 1;
    int l15 = l & 15, icq = l >> 4;

    const u16* HM = (const u16*)(wsb + OFF_HMOD) + (size_t)b * 128 * 128 * 256;
    const char* WB = wsb + OFF_W1C;
    const float* wsf = (const float*)wsb;

    int xdst[3]; const u16* xsrc[3]; bool xok[3]; bool xin[3];
    for (int j = 0; j < 3; ++j) {
        int q = t + j * 256;
        xok[j] = q < 720;
        int cell = q >> 2, part = q & 3;
        int hr = cell / 10, hc = cell - hr * 10;
        int ir = or0 + hr - 1, icol = col0 + hc - 1;
        xin[j] = (ir >= 0 && ir < 128 && icol >= 0 && icol < 128);
        xsrc[j] = HM + (ptrdiff_t)(ir * 128 + icol) * 256 + part * 8;
        xdst[j] = cell * 80 + part * 16;
    }

    int arow = wp * 8 + (l15 >> 3);
    int acol = l15 & 7;
    int aoff0 = (arow * 10 + acol) * 80 + icq * 16;
    int boff0 = (wo * 64 + l15) * 80 + icq * 16;

    f32x4 acc[4][4];
#pragma unroll
    for (int pf = 0; pf < 4; ++pf)
#pragma unroll
        for (int of = 0; of < 4; ++of) acc[pf][of] = (f32x4){0.f, 0.f, 0.f, 0.f};

    uint4 xr[3];
#pragma unroll
    for (int j = 0; j < 3; ++j) {
        uint4 z = {0, 0, 0, 0};
        xr[j] = (xok[j] && xin[j]) ? *(const uint4*)(xsrc[j]) : z;
    }
#pragma unroll
    for (int j = 0; j < 3; ++j)
        if (xok[j]) *(uint4*)(xb[0] + xdst[j]) = xr[j];
    {
        const char* wsrc = WB;  // tap 0, icb 0
        for (int off = w * 1024; off < 10240; off += 4096)
            gl_lds16(wsrc + off + octile * 10240 + l * 16, wb[0] + off);
    }
    __syncthreads();

    for (int icb = 0; icb < 8; ++icb) {
        if (icb + 1 < 8) {
#pragma unroll
            for (int j = 0; j < 3; ++j) {
                uint4 z = {0, 0, 0, 0};
                xr[j] = (xok[j] && xin[j]) ? *(const uint4*)(xsrc[j] + (icb + 1) * 32) : z;
            }
        }
#pragma unroll
        for (int tap = 0; tap < 9; ++tap) {
            int step = icb * 9 + tap;
            int ntap = tap + 1, nicb = icb;
            if (ntap == 9) { ntap = 0; nicb = icb + 1; }
            if (nicb < 8) {
                const char* wsrc = WB + (size_t)(ntap * 8 + nicb) * 20480 + octile * 10240;
                char* wdst = wb[(step + 1) & 1];
                for (int off = w * 1024; off < 10240; off += 4096)
                    gl_lds16(wsrc + off + l * 16, wdst + off);
            }
            if (tap == 8 && icb + 1 < 8) {
#pragma unroll
                for (int j = 0; j < 3; ++j)
                    if (xok[j]) *(uint4*)(xb[(icb + 1) & 1] + xdst[j]) = xr[j];
            }
            {
                const char* xc = xb[icb & 1];
                const char* wc = wb[step & 1];
                int jy = tap / 3, jx = tap - jy * 3;
                int ab = aoff0 + jy * 800 + jx * 80;
                bf16x8 af[4], bfr[4];
#pragma unroll
                for (int pf = 0; pf < 4; ++pf)
                    af[pf] = *(const bf16x8*)(xc + ab + pf * 1600);
#pragma unroll
                for (int of = 0; of < 4; ++of)
                    bfr[of] = *(const bf16x8*)(wc + boff0 + of * 1280);
#pragma unroll
                for (int pf = 0; pf < 4; ++pf)
#pragma unroll
                    for (int of = 0; of < 4; ++of)
                        acc[pf][of] = __builtin_amdgcn_mfma_f32_16x16x32_bf16(
                            af[pf], bfr[of], acc[pf][of], 0, 0, 0);
            }
            __syncthreads();
        }
    }

    float ns1 = ns1p[0];
    float d1v[4], bv[4];
    int ocg[4];
#pragma unroll
    for (int of = 0; of < 4; ++of) {
        int oc = octile * 128 + wo * 64 + of * 16 + l15;
        ocg[of] = oc;
        d1v[of] = wsf[10240 + b * 256 + oc];
        bv[of]  = bias1[oc];
    }
#pragma unroll
    for (int pf = 0; pf < 4; ++pf) {
#pragma unroll
        for (int r = 0; r < 4; ++r) {
            int pos = wp * 64 + pf * 16 + icq * 4 + r;
            int oy = or0 + (pos >> 3), ox = col0 + (pos & 7);
            float nz = ns1 * noise1[((size_t)b * 128 + oy) * 128 + ox];
#pragma unroll
            for (int of = 0; of < 4; ++of) {
                float v = lrelu2(acc[pf][of][r] * d1v[of] + nz + bv[of]);
                out[((size_t)(b * 256 + ocg[of]) * 128 + oy) * 128 + ox] = v;
            }
        }
    }
}

// ---------------- to_rgb (reads f32 h2 from out) ----------------
__global__ __launch_bounds__(256) void k_torgb(
    const float* __restrict__ yin, const float* __restrict__ w2,
    const float* __restrict__ bias2, float* __restrict__ out,
    const float* __restrict__ wsf)
{
    int idx = blockIdx.x * 256 + threadIdx.x;
    int xq = idx & 127, yq = (idx >> 7) & 127, b = idx >> 14;

    const float* s2 = wsf + 6144 + (size_t)b * 256;
    const float* hp = out + (size_t)b * 256 * 16384 + (size_t)yq * 128 + xq;

    float a0 = 0.f, a1 = 0.f, a2 = 0.f;
    for (int o = 0; o < 256; ++o) {
        float sv = hp[(size_t)o * 16384] * s2[o];
        a0 += sv * w2[o];
        a1 += sv * w2[256 + o];
        a2 += sv * w2[512 + o];
    }

    int py = yq & 1, px = xq & 1;
    float wy0 = py ? 0.75f : 0.25f, wy1 = py ? 0.25f : 0.75f;
    float wx0 = px ? 0.75f : 0.25f, wx1 = px ? 0.25f : 0.75f;
    int iy0 = (yq >> 1) + (py ? 0 : -1), iy1 = iy0 + 1;
    int ix0 = (xq >> 1) + (px ? 0 : -1), ix1 = ix0 + 1;
    bool vy0 = (unsigned)iy0 < 64u, vy1 = (unsigned)iy1 < 64u;
    bool vx0 = (unsigned)ix0 < 64u, vx1 = (unsigned)ix1 < 64u;

    float* out1 = out + (size_t)33554432;
    for (int c = 0; c < 3; ++c) {
        const float* yb = yin + ((size_t)b * 3 + c) * 4096;
        float sk = 0.f;
        if (vy0 && vx0) sk += wy0 * wx0 * yb[iy0 * 64 + ix0];
        if (vy0 && vx1) sk += wy0 * wx1 * yb[iy0 * 64 + ix1];
        if (vy1 && vx0) sk += wy1 * wx0 * yb[iy1 * 64 + ix0];
        if (vy1 && vx1) sk += wy1 * wx1 * yb[iy1 * 64 + ix1];
        float a = (c == 0) ? a0 : (c == 1) ? a1 : a2;
        out1[(((size_t)b * 3 + c) * 128 + yq) * 128 + xq] = a * 0.0625f + bias2[c] + sk;
    }
}

// ---------------------------------------------------------------------------
extern "C" void kernel_launch(void* const* d_in, const int* in_sizes, int n_in,
                              void* d_out, int out_size, void* d_ws, size_t ws_size,
                              hipStream_t stream)
{
    const float* x       = (const float*)d_in[0];
    const float* dl      = (const float*)d_in[1];
    const float* yin     = (const float*)d_in[2];
    const float* noise0  = (const float*)d_in[3];
    const float* noise1  = (const float*)d_in[4];
    const float* w0      = (const float*)d_in[5];
    const float* m0w     = (const float*)d_in[6];
    const float* m0b     = (const float*)d_in[7];
    const float* bias0   = (const float*)d_in[8];
    const float* ns0     = (const float*)d_in[9];
    const float* w1      = (const float*)d_in[10];
    const float* m1w     = (const float*)d_in[11];
    const float* m1b     = (const float*)d_in[12];
    const float* bias1   = (const float*)d_in[13];
    const float* ns1     = (const float*)d_in[14];
    const float* w2      = (const float*)d_in[15];
    const float* m2w     = (const float*)d_in[16];
    const float* m2b     = (const float*)d_in[17];
    const float* bias2   = (const float*)d_in[18];

    char*  wsb = (char*)d_ws;
    float* wsf = (float*)d_ws;
    float* out = (float*)d_out;

    k_styles<<<32, 256, 0, stream>>>(dl, m0w, m0b, m1w, m1b, m2w, m2b, wsf);
    k_demod <<<512, 256, 0, stream>>>(w0, w1, wsf);
    k_prepw0<<<512, 256, 0, stream>>>(w0, wsb);
    k_prepw1<<<256, 256, 0, stream>>>(w1, wsb);
    k_xmod  <<<512, 256, 0, stream>>>(x, wsb);
    k_conv0m<<<2048, 256, 0, stream>>>(wsb, noise0, bias0, ns0);
    k_conv1m<<<2048, 256, 0, stream>>>(wsb, noise1, bias1, ns1, out);
    k_torgb <<<512, 256, 0, stream>>>(yin, w2, bias2, out, wsf);
}